// Round 1
// baseline (159.763 us; speedup 1.0000x reference)
//
#include <hip/hip_runtime.h>
#include <stdint.h>

typedef __bf16 bf16_t;
typedef bf16_t bf16x8 __attribute__((ext_vector_type(8)));
typedef float f32x4 __attribute__((ext_vector_type(4)));
typedef unsigned short u16;
typedef u16 u16x8 __attribute__((ext_vector_type(8)));

#define N_    64
#define C_    64
#define W_    4096
#define F_    64
#define WW_   16
#define OUTW  4081
#define TT    128      // output t per block
#define TROWS 144      // staged x rows (TT + WW - 1 rounded up)
#define CPAD  72       // LDS row stride in elements (bank spread)
#define KCH   4        // ksteps per w chunk
#define NCH   8        // 32 ksteps total / KCH

__device__ __forceinline__ u16 f2bf(float f) {
  union { float f; uint32_t u; } v; v.f = f;
  uint32_t u = v.u;
  u += 0x7fffu + ((u >> 16) & 1u);   // RNE
  return (u16)(u >> 16);
}

// Pre-pack w into exact B-fragment lane order, bf16.
// flat idx = ((kstep*4 + fg)*64 + lane)*8 + j
// value = w[f = fg*16 + (lane&15)][c][kk],  k = kstep*32 + 8*(lane>>4) + j,
// K-order: k = kk*64 + c  (channel-minor)
__global__ void pack_w_kernel(const float* __restrict__ w, u16* __restrict__ wp) {
  int idx = blockIdx.x * 256 + threadIdx.x;       // 65536 total
  int j     = idx & 7;
  int lane  = (idx >> 3) & 63;
  int fg    = (idx >> 9) & 3;
  int kstep = idx >> 11;
  int f  = fg * 16 + (lane & 15);
  int kg = kstep * 32 + 8 * (lane >> 4) + j;
  int kk = kg >> 6;
  int c  = kg & 63;
  wp[idx] = f2bf(w[(f * C_ + c) * WW_ + kk]);
}

__launch_bounds__(256, 4)
__global__ void conv_kernel(const float* __restrict__ x, const u16* __restrict__ wp,
                            const float* __restrict__ bias, float* __restrict__ out) {
  __shared__ __align__(16) u16 xT[TROWS * CPAD];   // [t'][c], bf16 bits
  __shared__ __align__(16) u16 wbuf[KCH * 2048];   // one w chunk

  const int tid  = threadIdx.x;
  const int lane = tid & 63;
  const int wid  = tid >> 6;
  const int n    = blockIdx.y;
  const int t0   = blockIdx.x * TT;

  // ---- stage x tile: global f32 [c][t] -> LDS bf16 [t'][c] ----
  const float* xn = x + (size_t)n * C_ * W_;
  for (int task = tid; task < 8 * TROWS; task += 256) {
    int tp = task % TROWS;          // t' within tile
    int cg = task / TROWS;          // channel-group of 8
    int tg = t0 + tp; if (tg > W_ - 1) tg = W_ - 1;   // clamp halo (unused outputs)
    u16x8 v;
#pragma unroll
    for (int i = 0; i < 8; ++i)
      v[i] = f2bf(xn[(size_t)(cg * 8 + i) * W_ + tg]);
    *reinterpret_cast<u16x8*>(&xT[tp * CPAD + cg * 8]) = v;   // 16B, balanced banks
  }

  f32x4 acc[2][4];
#pragma unroll
  for (int a = 0; a < 2; ++a)
#pragma unroll
    for (int g = 0; g < 4; ++g)
      acc[a][g] = (f32x4){0.f, 0.f, 0.f, 0.f};

  const int rowbase = wid * 32 + (lane & 15);   // A-frag row (t offset in tile)
  const int csub    = 8 * (lane >> 4);          // A-frag channel sub-offset

  for (int ch = 0; ch < NCH; ++ch) {
    __syncthreads();   // protect wbuf from previous iteration's readers
    // ---- stage w chunk (16 KB) via global_load_lds width=16 ----
    {
      const u16* src = wp + ch * (KCH * 2048) + wid * 2048 + lane * 8;
      u16* dst = &wbuf[wid * 2048];
#pragma unroll
      for (int i = 0; i < 4; ++i) {
        __builtin_amdgcn_global_load_lds(
            (const __attribute__((address_space(1))) uint32_t*)(src + i * 512),
            (__attribute__((address_space(3))) uint32_t*)(dst + i * 512),
            16, 0, 0);
      }
    }
    __syncthreads();   // drains vmcnt

#pragma unroll
    for (int s = 0; s < KCH; ++s) {
      const int kstep = ch * KCH + s;
      const int kk = kstep >> 1;            // tap index (const per kstep)
      const int cb = (kstep & 1) * 32;      // channel base 0 / 32
      const u16* arow = &xT[(rowbase + kk) * CPAD + cb + csub];
      bf16x8 a0 = *reinterpret_cast<const bf16x8*>(arow);
      bf16x8 a1 = *reinterpret_cast<const bf16x8*>(arow + 16 * CPAD);
#pragma unroll
      for (int fg = 0; fg < 4; ++fg) {
        bf16x8 bb = *reinterpret_cast<const bf16x8*>(&wbuf[s * 2048 + fg * 512 + lane * 8]);
        acc[0][fg] = __builtin_amdgcn_mfma_f32_16x16x32_bf16(a0, bb, acc[0][fg], 0, 0, 0);
        acc[1][fg] = __builtin_amdgcn_mfma_f32_16x16x32_bf16(a1, bb, acc[1][fg], 0, 0, 0);
      }
    }
  }

  // ---- epilogue: C/D layout col=lane&15, row=(lane>>4)*4+reg ----
  const int fcol = lane & 15;
  const int rq   = (lane >> 4) * 4;
  float bv[4];
#pragma unroll
  for (int fg = 0; fg < 4; ++fg) bv[fg] = bias[fg * 16 + fcol];

#pragma unroll
  for (int rf = 0; rf < 2; ++rf) {
#pragma unroll
    for (int fg = 0; fg < 4; ++fg) {
#pragma unroll
      for (int r = 0; r < 4; ++r) {
        int t = t0 + wid * 32 + rf * 16 + rq + r;
        if (t < OUTW)
          out[((size_t)n * F_ + fg * 16 + fcol) * OUTW + t] = acc[rf][fg][r] + bv[fg];
      }
    }
  }
}

extern "C" void kernel_launch(void* const* d_in, const int* in_sizes, int n_in,
                              void* d_out, int out_size, void* d_ws, size_t ws_size,
                              hipStream_t stream) {
  const float* x = (const float*)d_in[0];
  const float* w = (const float*)d_in[1];
  const float* b = (const float*)d_in[2];
  float* out = (float*)d_out;
  u16* wp = (u16*)d_ws;   // 131072 bytes used

  hipLaunchKernelGGL(pack_w_kernel, dim3(256), dim3(256), 0, stream, w, wp);
  dim3 grid((OUTW + TT - 1) / TT, N_);   // 32 x 64
  hipLaunchKernelGGL(conv_kernel, grid, dim3(256), 0, stream, x, wp, b, out);
}

// Round 2
// 152.128 us; speedup vs baseline: 1.0502x; 1.0502x over previous
//
#include <hip/hip_runtime.h>
#include <stdint.h>

typedef __bf16 bf16_t;
typedef bf16_t bf16x8 __attribute__((ext_vector_type(8)));
typedef float f32x4 __attribute__((ext_vector_type(4)));
typedef unsigned short u16;
typedef u16 u16x8 __attribute__((ext_vector_type(8)));

#define N_    64
#define C_    64
#define W_    4096
#define F_    64
#define WW_   16
#define OUTW  4081
#define TT    128      // output t per block
#define TROWS 144      // staged x rows (TT + WW - 1 rounded up)
#define CPAD  72       // xT row stride (u16 elems); 16B-aligned rows
#define OPAD  65       // obuf row stride (f32 elems); conflict-free transpose
#define NKS   32       // K steps (K=1024 / 32)

__device__ __forceinline__ u16 f2bf(float f) {
  union { float f; uint32_t u; } v; v.f = f;
  uint32_t u = v.u;
  u += 0x7fffu + ((u >> 16) & 1u);   // RNE
  return (u16)(u >> 16);
}

// Pre-pack w into exact B-fragment lane order, bf16.
// flat idx = ((kstep*4 + fg)*64 + lane)*8 + j
// value = w[f = fg*16 + (lane&15)][c][kk],  k = kstep*32 + 8*(lane>>4) + j,
// K-order: k = kk*64 + c  (channel-minor)
__global__ void pack_w_kernel(const float* __restrict__ w, u16* __restrict__ wp) {
  int idx = blockIdx.x * 256 + threadIdx.x;       // 65536 total
  int j     = idx & 7;
  int lane  = (idx >> 3) & 63;
  int fg    = (idx >> 9) & 3;
  int kstep = idx >> 11;
  int f  = fg * 16 + (lane & 15);
  int kg = kstep * 32 + 8 * (lane >> 4) + j;
  int kk = kg >> 6;
  int c  = kg & 63;
  wp[idx] = f2bf(w[(f * C_ + c) * WW_ + kk]);
}

__launch_bounds__(256, 4)
__global__ void conv_kernel(const float* __restrict__ x, const u16* __restrict__ wp,
                            const float* __restrict__ bias, float* __restrict__ out) {
  // Union: xT (bf16 [t'][c], 20736 B) during main loop; obuf (f32 [t][f], 33280 B) in epilogue.
  __shared__ __align__(16) char smem_raw[TT * OPAD * 4];
  u16*   xT   = reinterpret_cast<u16*>(smem_raw);
  float* obuf = reinterpret_cast<float*>(smem_raw);

  const int tid  = threadIdx.x;
  const int lane = tid & 63;
  const int wid  = tid >> 6;
  const int n    = blockIdx.y;
  const int t0   = blockIdx.x * TT;

  // ---- stage x tile once: global f32 [c][t] -> LDS bf16 [t'][c] ----
  const float* xn = x + (size_t)n * C_ * W_;
  for (int task = tid; task < 8 * TROWS; task += 256) {
    int tp = task % TROWS;          // t' within tile
    int cg = task / TROWS;          // channel-group of 8
    int tg = t0 + tp; if (tg > W_ - 1) tg = W_ - 1;   // clamp halo (unused outputs)
    u16x8 v;
#pragma unroll
    for (int i = 0; i < 8; ++i)
      v[i] = f2bf(xn[(size_t)(cg * 8 + i) * W_ + tg]);
    *reinterpret_cast<u16x8*>(&xT[tp * CPAD + cg * 8]) = v;
  }
  __syncthreads();

  f32x4 acc[2][4];
#pragma unroll
  for (int a = 0; a < 2; ++a)
#pragma unroll
    for (int g = 0; g < 4; ++g)
      acc[a][g] = (f32x4){0.f, 0.f, 0.f, 0.f};

  const int rowbase = wid * 32 + (lane & 15);   // A-frag row (t offset in tile)
  const int csub    = 8 * (lane >> 4);          // A-frag channel sub-offset
  const u16* wpB    = wp + (size_t)lane * 8;    // B frags: L2-resident, coalesced 16B/lane

  // ---- barrier-free main loop: per kstep 2 ds_read_b128 + 4 L2 loads + 8 MFMA ----
#pragma unroll 4
  for (int ks = 0; ks < NKS; ++ks) {
    const int kk = ks >> 1;               // tap index
    const int cb = (ks & 1) << 5;         // channel base 0 / 32
    const u16* arow = &xT[(rowbase + kk) * CPAD + cb + csub];
    bf16x8 a0 = *reinterpret_cast<const bf16x8*>(arow);
    bf16x8 a1 = *reinterpret_cast<const bf16x8*>(arow + 16 * CPAD);
    bf16x8 b0 = *reinterpret_cast<const bf16x8*>(wpB + (size_t)(ks * 4 + 0) * 512);
    bf16x8 b1 = *reinterpret_cast<const bf16x8*>(wpB + (size_t)(ks * 4 + 1) * 512);
    bf16x8 b2 = *reinterpret_cast<const bf16x8*>(wpB + (size_t)(ks * 4 + 2) * 512);
    bf16x8 b3 = *reinterpret_cast<const bf16x8*>(wpB + (size_t)(ks * 4 + 3) * 512);
    acc[0][0] = __builtin_amdgcn_mfma_f32_16x16x32_bf16(a0, b0, acc[0][0], 0, 0, 0);
    acc[1][0] = __builtin_amdgcn_mfma_f32_16x16x32_bf16(a1, b0, acc[1][0], 0, 0, 0);
    acc[0][1] = __builtin_amdgcn_mfma_f32_16x16x32_bf16(a0, b1, acc[0][1], 0, 0, 0);
    acc[1][1] = __builtin_amdgcn_mfma_f32_16x16x32_bf16(a1, b1, acc[1][1], 0, 0, 0);
    acc[0][2] = __builtin_amdgcn_mfma_f32_16x16x32_bf16(a0, b2, acc[0][2], 0, 0, 0);
    acc[1][2] = __builtin_amdgcn_mfma_f32_16x16x32_bf16(a1, b2, acc[1][2], 0, 0, 0);
    acc[0][3] = __builtin_amdgcn_mfma_f32_16x16x32_bf16(a0, b3, acc[0][3], 0, 0, 0);
    acc[1][3] = __builtin_amdgcn_mfma_f32_16x16x32_bf16(a1, b3, acc[1][3], 0, 0, 0);
  }

  // ---- epilogue: acc -> LDS [t][f] (stride 65: both sides <=2-way banks) -> coalesced stores ----
  const int fcol = lane & 15;
  const int rq   = (lane >> 4) * 4;
  float bv[4];
#pragma unroll
  for (int fg = 0; fg < 4; ++fg) bv[fg] = bias[fg * 16 + fcol];

  __syncthreads();   // all waves done reading xT before obuf overwrites it
#pragma unroll
  for (int rf = 0; rf < 2; ++rf)
#pragma unroll
    for (int fg = 0; fg < 4; ++fg)
#pragma unroll
      for (int r = 0; r < 4; ++r)
        obuf[(wid * 32 + rf * 16 + rq + r) * OPAD + fg * 16 + fcol] = acc[rf][fg][r] + bv[fg];
  __syncthreads();

  // 8192 floats: p = f*128 + tl; consecutive lanes -> consecutive t -> coalesced dword stores
#pragma unroll
  for (int i = 0; i < 32; ++i) {
    int p  = tid + 256 * i;
    int f  = p >> 7;
    int tl = p & 127;
    int t  = t0 + tl;
    if (t < OUTW)
      out[((size_t)n * F_ + f) * OUTW + t] = obuf[tl * OPAD + f];
  }
}

extern "C" void kernel_launch(void* const* d_in, const int* in_sizes, int n_in,
                              void* d_out, int out_size, void* d_ws, size_t ws_size,
                              hipStream_t stream) {
  const float* x = (const float*)d_in[0];
  const float* w = (const float*)d_in[1];
  const float* b = (const float*)d_in[2];
  float* out = (float*)d_out;
  u16* wp = (u16*)d_ws;   // 131072 bytes used

  hipLaunchKernelGGL(pack_w_kernel, dim3(256), dim3(256), 0, stream, w, wp);
  dim3 grid((OUTW + TT - 1) / TT, N_);   // 32 x 64
  hipLaunchKernelGGL(conv_kernel, grid, dim3(256), 0, stream, x, wp, b, out);
}

// Round 3
// 143.632 us; speedup vs baseline: 1.1123x; 1.0592x over previous
//
#include <hip/hip_runtime.h>
#include <stdint.h>

typedef __bf16 bf16_t;
typedef bf16_t bf16x8 __attribute__((ext_vector_type(8)));
typedef float f32x4 __attribute__((ext_vector_type(4)));
typedef unsigned short u16;
typedef u16 u16x8 __attribute__((ext_vector_type(8)));

#define N_    64
#define C_    64
#define W_    4096
#define F_    64
#define WW_   16
#define OUTW  4081
#define TT    256      // output t per block (N dim of GEMM)
#define TROWS 271      // staged x rows (TT + WW - 1)
#define CPAD  72       // xT row stride (u16 elems); rows 16B-aligned (144 B)
#define NKS   32       // K steps (K=1024 / 32)

__device__ __forceinline__ u16 f2bf(float f) {
  union { float f; uint32_t u; } v; v.f = f;
  uint32_t u = v.u;
  u += 0x7fffu + ((u >> 16) & 1u);   // RNE
  return (u16)(u >> 16);
}

// Pre-pack w into exact MFMA A-fragment lane order, bf16 (layout unchanged from r2;
// the same packing serves A-side now: row=f=lane&15(+16*m), k=8*(lane>>4)+j).
// flat idx = ((kstep*4 + m)*64 + lane)*8 + j
// value = w[f = m*16 + (lane&15)][c][kk], kk = kstep>>1, c = (kstep&1)*32 + 8*(lane>>4)+j
__global__ void pack_w_kernel(const float* __restrict__ w, u16* __restrict__ wp) {
  int idx = blockIdx.x * 256 + threadIdx.x;       // 65536 total
  int j     = idx & 7;
  int lane  = (idx >> 3) & 63;
  int m     = (idx >> 9) & 3;
  int kstep = idx >> 11;
  int f  = m * 16 + (lane & 15);
  int kg = kstep * 32 + 8 * (lane >> 4) + j;
  int kk = kg >> 6;
  int c  = kg & 63;
  wp[idx] = f2bf(w[(f * C_ + c) * WW_ + kk]);
}

__attribute__((amdgpu_waves_per_eu(4, 4)))
__launch_bounds__(256)
__global__ void conv_kernel(const float* __restrict__ x, const u16* __restrict__ wp,
                            const float* __restrict__ bias, float* __restrict__ out) {
  __shared__ __align__(16) u16 xT[TROWS * CPAD];   // 39024 B -> 4 blocks/CU

  const int tid  = threadIdx.x;
  const int lane = tid & 63;
  const int wid  = tid >> 6;
  const int n    = blockIdx.y;
  const int t0   = blockIdx.x * TT;

  // ---- stage x tile once: global f32 [c][t] -> LDS bf16 [t'][c] ----
  const float* xn = x + (size_t)n * C_ * W_;
  for (int task = tid; task < 8 * TROWS; task += 256) {
    int tp = task % TROWS;          // t' within tile
    int cg = task / TROWS;          // channel-group of 8
    int tg = t0 + tp; if (tg > W_ - 1) tg = W_ - 1;   // clamp halo (outputs unused)
    u16x8 v;
#pragma unroll
    for (int i = 0; i < 8; ++i)
      v[i] = f2bf(xn[(size_t)(cg * 8 + i) * W_ + tg]);
    *reinterpret_cast<u16x8*>(&xT[tp * CPAD + cg * 8]) = v;
  }
  __syncthreads();

  f32x4 acc[4][4];   // [m: f-quad][nf: t-quad]
#pragma unroll
  for (int a = 0; a < 4; ++a)
#pragma unroll
    for (int g = 0; g < 4; ++g)
      acc[a][g] = (f32x4){0.f, 0.f, 0.f, 0.f};

  const int fr = lane & 15;           // frag row/col index
  const int kq = lane >> 4;           // k sub-quad
  const u16* wpA = wp + (size_t)lane * 8;            // packed A frags (L2-resident)
  const u16* xB  = &xT[(wid * 64 + fr) * CPAD + 8 * kq];  // B frag base in LDS

  // ---- main loop: full unroll, explicit 1-deep A prefetch ----
  bf16x8 ca0 = *reinterpret_cast<const bf16x8*>(wpA + 0 * 512);
  bf16x8 ca1 = *reinterpret_cast<const bf16x8*>(wpA + 1 * 512);
  bf16x8 ca2 = *reinterpret_cast<const bf16x8*>(wpA + 2 * 512);
  bf16x8 ca3 = *reinterpret_cast<const bf16x8*>(wpA + 3 * 512);

#pragma unroll
  for (int ks = 0; ks < NKS; ++ks) {
    const int kk = ks >> 1;               // tap index
    const int cb = (ks & 1) << 5;         // channel base 0 / 32
    // prefetch next kstep's A frags (L2) while this kstep's MFMAs run
    bf16x8 na0, na1, na2, na3;
    if (ks < NKS - 1) {
      na0 = *reinterpret_cast<const bf16x8*>(wpA + (size_t)((ks + 1) * 4 + 0) * 512);
      na1 = *reinterpret_cast<const bf16x8*>(wpA + (size_t)((ks + 1) * 4 + 1) * 512);
      na2 = *reinterpret_cast<const bf16x8*>(wpA + (size_t)((ks + 1) * 4 + 2) * 512);
      na3 = *reinterpret_cast<const bf16x8*>(wpA + (size_t)((ks + 1) * 4 + 3) * 512);
    }
    // B frags (x) from LDS: 4 t-quads, 16 rows apart
    bf16x8 b0 = *reinterpret_cast<const bf16x8*>(xB + (kk +  0) * CPAD + cb);
    bf16x8 b1 = *reinterpret_cast<const bf16x8*>(xB + (kk + 16) * CPAD + cb);
    bf16x8 b2 = *reinterpret_cast<const bf16x8*>(xB + (kk + 32) * CPAD + cb);
    bf16x8 b3 = *reinterpret_cast<const bf16x8*>(xB + (kk + 48) * CPAD + cb);

    acc[0][0] = __builtin_amdgcn_mfma_f32_16x16x32_bf16(ca0, b0, acc[0][0], 0, 0, 0);
    acc[1][0] = __builtin_amdgcn_mfma_f32_16x16x32_bf16(ca1, b0, acc[1][0], 0, 0, 0);
    acc[2][0] = __builtin_amdgcn_mfma_f32_16x16x32_bf16(ca2, b0, acc[2][0], 0, 0, 0);
    acc[3][0] = __builtin_amdgcn_mfma_f32_16x16x32_bf16(ca3, b0, acc[3][0], 0, 0, 0);
    acc[0][1] = __builtin_amdgcn_mfma_f32_16x16x32_bf16(ca0, b1, acc[0][1], 0, 0, 0);
    acc[1][1] = __builtin_amdgcn_mfma_f32_16x16x32_bf16(ca1, b1, acc[1][1], 0, 0, 0);
    acc[2][1] = __builtin_amdgcn_mfma_f32_16x16x32_bf16(ca2, b1, acc[2][1], 0, 0, 0);
    acc[3][1] = __builtin_amdgcn_mfma_f32_16x16x32_bf16(ca3, b1, acc[3][1], 0, 0, 0);
    acc[0][2] = __builtin_amdgcn_mfma_f32_16x16x32_bf16(ca0, b2, acc[0][2], 0, 0, 0);
    acc[1][2] = __builtin_amdgcn_mfma_f32_16x16x32_bf16(ca1, b2, acc[1][2], 0, 0, 0);
    acc[2][2] = __builtin_amdgcn_mfma_f32_16x16x32_bf16(ca2, b2, acc[2][2], 0, 0, 0);
    acc[3][2] = __builtin_amdgcn_mfma_f32_16x16x32_bf16(ca3, b2, acc[3][2], 0, 0, 0);
    acc[0][3] = __builtin_amdgcn_mfma_f32_16x16x32_bf16(ca0, b3, acc[0][3], 0, 0, 0);
    acc[1][3] = __builtin_amdgcn_mfma_f32_16x16x32_bf16(ca1, b3, acc[1][3], 0, 0, 0);
    acc[2][3] = __builtin_amdgcn_mfma_f32_16x16x32_bf16(ca2, b3, acc[2][3], 0, 0, 0);
    acc[3][3] = __builtin_amdgcn_mfma_f32_16x16x32_bf16(ca3, b3, acc[3][3], 0, 0, 0);

    ca0 = na0; ca1 = na1; ca2 = na2; ca3 = na3;
  }

  // ---- epilogue: D row=(lane>>4)*4+r = f, col=lane&15 = t -> direct stores,
  //      each instr writes 4 x 64B contiguous segments (t-contiguous) ----
  f32x4 bv[4];
#pragma unroll
  for (int m = 0; m < 4; ++m)
    bv[m] = *reinterpret_cast<const f32x4*>(bias + m * 16 + kq * 4);

#pragma unroll
  for (int m = 0; m < 4; ++m) {
#pragma unroll
    for (int nf = 0; nf < 4; ++nf) {
      int t = t0 + wid * 64 + nf * 16 + fr;
      if (t < OUTW) {
#pragma unroll
        for (int r = 0; r < 4; ++r) {
          int f = m * 16 + kq * 4 + r;
          out[((size_t)n * F_ + f) * OUTW + t] = acc[m][nf][r] + bv[m][r];
        }
      }
    }
  }
}

extern "C" void kernel_launch(void* const* d_in, const int* in_sizes, int n_in,
                              void* d_out, int out_size, void* d_ws, size_t ws_size,
                              hipStream_t stream) {
  const float* x = (const float*)d_in[0];
  const float* w = (const float*)d_in[1];
  const float* b = (const float*)d_in[2];
  float* out = (float*)d_out;
  u16* wp = (u16*)d_ws;   // 131072 bytes used

  hipLaunchKernelGGL(pack_w_kernel, dim3(256), dim3(256), 0, stream, w, wp);
  dim3 grid((OUTW + TT - 1) / TT, N_);   // 16 x 64 = 1024 blocks = 4/CU
  hipLaunchKernelGGL(conv_kernel, grid, dim3(256), 0, stream, x, wp, b, out);
}

// Round 5
// 135.803 us; speedup vs baseline: 1.1764x; 1.0577x over previous
//
#include <hip/hip_runtime.h>
#include <stdint.h>

typedef __bf16 bf16_t;
typedef bf16_t bf16x8 __attribute__((ext_vector_type(8)));
typedef float f32x4 __attribute__((ext_vector_type(4)));
typedef float f32x16 __attribute__((ext_vector_type(16)));
typedef unsigned short u16;
typedef u16 u16x8 __attribute__((ext_vector_type(8)));

#define N_    64
#define C_    64
#define W_    4096
#define F_    64
#define WW_   16
#define OUTW  4081
#define TT    256      // output t per block
#define TROWS 271      // staged x rows (TT + WW - 1)
#define CPAD  72       // xT row stride (u16); rows 16B-aligned (144 B)
#define NKS   64       // K steps of 16 (K = 1024)

__device__ __forceinline__ u16 f2bf(float f) {
  union { float f; uint32_t u; } v; v.f = f;
  uint32_t u = v.u;
  u += 0x7fffu + ((u >> 16) & 1u);   // RNE
  return (u16)(u >> 16);
}

// Pack w into 32x32x16 A-fragment lane order, bf16.
// flat idx = ((ks*2 + m)*64 + lane)*8 + j
// A layout: row f = m*32 + (lane&31), k = (lane>>5)*8 + j (8 consecutive k)
// K-order: k_global = ks*16 + klocal;  k = kk*64 + c  (channel-minor)
__global__ void pack_w_kernel(const float* __restrict__ w, u16* __restrict__ wp) {
  int idx = blockIdx.x * 256 + threadIdx.x;       // 65536 total
  int j    = idx & 7;
  int lane = (idx >> 3) & 63;
  int m    = (idx >> 9) & 1;
  int ks   = idx >> 10;
  int f  = m * 32 + (lane & 31);
  int kg = ks * 16 + (lane >> 5) * 8 + j;
  int kk = kg >> 6;
  int c  = kg & 63;
  wp[idx] = f2bf(w[(f * C_ + c) * WW_ + kk]);
}

__attribute__((amdgpu_waves_per_eu(3, 4)))
__launch_bounds__(256)
__global__ void conv_kernel(const float* __restrict__ x, const u16* __restrict__ wp,
                            const float* __restrict__ bias, float* __restrict__ out) {
  __shared__ __align__(16) u16 xT[TROWS * CPAD];   // 39024 B

  const int tid  = threadIdx.x;
  const int lane = tid & 63;
  const int wid  = tid >> 6;
  const int n    = blockIdx.y;
  const int t0   = blockIdx.x * TT;

  // ---- stage x tile once: global f32 [c][t] -> LDS bf16 [t'][c] ----
  const float* xn = x + (size_t)n * C_ * W_;
  for (int task = tid; task < 8 * TROWS; task += 256) {
    int tp = task % TROWS;
    int cg = task / TROWS;
    int tg = t0 + tp; if (tg > W_ - 1) tg = W_ - 1;   // clamped halo feeds discarded t only
    u16x8 v;
#pragma unroll
    for (int i = 0; i < 8; ++i)
      v[i] = f2bf(xn[(size_t)(cg * 8 + i) * W_ + tg]);
    *reinterpret_cast<u16x8*>(&xT[tp * CPAD + cg * 8]) = v;
  }
  __syncthreads();

  f32x16 acc[2][2];   // [m: f-32-tile][nt: t-32-tile]
#pragma unroll
  for (int a = 0; a < 2; ++a)
#pragma unroll
    for (int g = 0; g < 2; ++g)
      acc[a][g] = (f32x16){0.f,0.f,0.f,0.f,0.f,0.f,0.f,0.f,0.f,0.f,0.f,0.f,0.f,0.f,0.f,0.f};

  const int rowt = lane & 31;         // t index within 32-tile (B col / D col)
  const int hi   = lane >> 5;         // k-half selector
  const int browt = wid * 64 + rowt;  // wave's t-row base in xT
  const u16* wpA  = wp + (size_t)lane * 8;   // A frags, L2-resident, 16B/lane coalesced

  // A frag for (ks,m): wpA + (ks*2+m)*512 elems
#define LA(ks, m) (*reinterpret_cast<const bf16x8*>(wpA + (size_t)((ks) * 2 + (m)) * 512))
  // B frag for (ks,nt): row = browt + nt*32 + (ks>>2), col = (ks&3)*16 + hi*8
#define LB(ks, nt) (*reinterpret_cast<const bf16x8*>( \
      &xT[(browt + (nt) * 32 + ((ks) >> 2)) * CPAD + ((ks) & 3) * 16 + hi * 8]))

  bf16x8 ap[3][2];   // depth-3 A pipeline (global/L2)
  bf16x8 bp[2][2];   // depth-2 B pipeline (LDS)
  ap[0][0] = LA(0, 0); ap[0][1] = LA(0, 1);
  ap[1][0] = LA(1, 0); ap[1][1] = LA(1, 1);
  bp[0][0] = LB(0, 0); bp[0][1] = LB(0, 1);

#pragma unroll
  for (int ks = 0; ks < NKS; ++ks) {
    if (ks + 2 < NKS) {               // issue A loads 2 ksteps ahead
      ap[(ks + 2) % 3][0] = LA(ks + 2, 0);
      ap[(ks + 2) % 3][1] = LA(ks + 2, 1);
    }
    if (ks + 1 < NKS) {               // issue B ds_reads 1 kstep ahead
      bp[(ks + 1) & 1][0] = LB(ks + 1, 0);
      bp[(ks + 1) & 1][1] = LB(ks + 1, 1);
    }
    acc[0][0] = __builtin_amdgcn_mfma_f32_32x32x16_bf16(ap[ks % 3][0], bp[ks & 1][0], acc[0][0], 0, 0, 0);
    acc[0][1] = __builtin_amdgcn_mfma_f32_32x32x16_bf16(ap[ks % 3][0], bp[ks & 1][1], acc[0][1], 0, 0, 0);
    acc[1][0] = __builtin_amdgcn_mfma_f32_32x32x16_bf16(ap[ks % 3][1], bp[ks & 1][0], acc[1][0], 0, 0, 0);
    acc[1][1] = __builtin_amdgcn_mfma_f32_32x32x16_bf16(ap[ks % 3][1], bp[ks & 1][1], acc[1][1], 0, 0, 0);
  }
#undef LA
#undef LB

  // ---- epilogue: D col = lane&31 = t, row = (reg&3) + 8*(reg>>2) + 4*hi = f ----
  f32x4 bv[2][4];
#pragma unroll
  for (int m = 0; m < 2; ++m)
#pragma unroll
    for (int rq = 0; rq < 4; ++rq)
      bv[m][rq] = *reinterpret_cast<const f32x4*>(bias + m * 32 + rq * 8 + hi * 4);

#pragma unroll
  for (int m = 0; m < 2; ++m) {
#pragma unroll
    for (int nt = 0; nt < 2; ++nt) {
      int t = t0 + wid * 64 + nt * 32 + rowt;
      if (t < OUTW) {
#pragma unroll
        for (int rq = 0; rq < 4; ++rq) {
#pragma unroll
          for (int r2 = 0; r2 < 4; ++r2) {
            int f = m * 32 + hi * 4 + rq * 8 + r2;
            out[((size_t)n * F_ + f) * OUTW + t] = acc[m][nt][rq * 4 + r2] + bv[m][rq][r2];
          }
        }
      }
    }
  }
}

extern "C" void kernel_launch(void* const* d_in, const int* in_sizes, int n_in,
                              void* d_out, int out_size, void* d_ws, size_t ws_size,
                              hipStream_t stream) {
  const float* x = (const float*)d_in[0];
  const float* w = (const float*)d_in[1];
  const float* b = (const float*)d_in[2];
  float* out = (float*)d_out;
  u16* wp = (u16*)d_ws;   // 131072 bytes used

  hipLaunchKernelGGL(pack_w_kernel, dim3(256), dim3(256), 0, stream, w, wp);
  dim3 grid((OUTW + TT - 1) / TT, N_);   // 16 x 64 = 1024 blocks
  hipLaunchKernelGGL(conv_kernel, grid, dim3(256), 0, stream, x, wp, b, out);
}